// Round 1
// baseline (7170.711 us; speedup 1.0000x reference)
//
#include <hip/hip_runtime.h>

#define LLEN 131072
#define CDIM 64
#define NB 4

// ---------------- Kernel A: qp/kp GEMM -> dwconv (shuffle) -> Gram + norms ----
// grid = NB*256 blocks, 256 threads. Each block: 4 chunks of 128 positions.
// Waves 0,1 = q (positions 0..127), waves 2,3 = k (same positions).
__global__ __launch_bounds__(256, 2) void qk_gram_kernel(
    const float* __restrict__ x, const float* __restrict__ w_kv,
    const float* __restrict__ w_kv_dw, const float* __restrict__ w_q,
    const float* __restrict__ w_q_dw, float* __restrict__ G,
    float* __restrict__ nq, float* __restrict__ nk) {
  __shared__ float q_s[128][68];   // post-conv q, [l][c], pad 68 for banks/align
  __shared__ float k_s[128][68];
  __shared__ float edgeL[4][64];
  __shared__ float edgeR[4][64];

  const int tid  = threadIdx.x;
  const int lane = tid & 63;
  const int wvid = tid >> 6;
  const int pl   = tid & 127;       // position within tile
  const bool isK = tid >= 128;
  const int b    = blockIdx.x >> 8;
  const int blk  = blockIdx.x & 255;

  const float* wmat = isK ? w_kv : w_q;        // rows 0..63 of each
  const float* wdw  = isK ? w_kv_dw : w_q_dw;  // rows 0..63
  const float* xb   = x + (size_t)b * CDIM * LLEN;

  float g[16];
#pragma unroll
  for (int i = 0; i < 16; ++i) g[i] = 0.f;
  float nrm = 0.f;

  for (int ck = 0; ck < 4; ++ck) {
    const int l0 = (blk * 4 + ck) * 128;
    const int p  = l0 + pl;

    // ---- stage 1: pre-conv value at own position, all 64 out channels
    float x_reg[64];
#pragma unroll
    for (int ci = 0; ci < 64; ++ci) x_reg[ci] = xb[(size_t)ci * LLEN + p];
    float acc[64];
#pragma unroll
    for (int ch = 0; ch < 64; ++ch) {
      const float* wr = wmat + ch * 64;
      float p0 = 0.f, p1 = 0.f, p2 = 0.f, p3 = 0.f;
#pragma unroll
      for (int ci = 0; ci < 64; ci += 4) {
        p0 = fmaf(wr[ci + 0], x_reg[ci + 0], p0);
        p1 = fmaf(wr[ci + 1], x_reg[ci + 1], p1);
        p2 = fmaf(wr[ci + 2], x_reg[ci + 2], p2);
        p3 = fmaf(wr[ci + 3], x_reg[ci + 3], p3);
      }
      acc[ch] = (p0 + p1) + (p2 + p3);
    }

    // ---- halo pre-conv values (positions l0-1 / l0+128), one channel/thread
    {
      const int hc = lane;
      const int pH = (wvid & 1) ? (l0 + 128) : (l0 - 1);
      float hval = 0.f;
      if (pH >= 0 && pH < LLEN) {
        const float* wr = ((wvid < 2) ? w_q : w_kv) + hc * 64;
        float h0 = 0.f, h1 = 0.f, h2 = 0.f, h3 = 0.f;
#pragma unroll
        for (int ci = 0; ci < 64; ci += 4) {
          h0 = fmaf(wr[ci + 0], xb[(size_t)(ci + 0) * LLEN + pH], h0);
          h1 = fmaf(wr[ci + 1], xb[(size_t)(ci + 1) * LLEN + pH], h1);
          h2 = fmaf(wr[ci + 2], xb[(size_t)(ci + 2) * LLEN + pH], h2);
          h3 = fmaf(wr[ci + 3], xb[(size_t)(ci + 3) * LLEN + pH], h3);
        }
        hval = (h0 + h1) + (h2 + h3);
      }
      if (wvid == 0)      edgeL[0][hc] = hval;  // q left
      else if (wvid == 1) edgeR[1][hc] = hval;  // q right
      else if (wvid == 2) edgeL[2][hc] = hval;  // k left
      else                edgeR[3][hc] = hval;  // k right
    }
    // wave-boundary neighbor values
    if (lane == 63 && (wvid == 0 || wvid == 2)) {
#pragma unroll
      for (int ch = 0; ch < 64; ++ch) edgeL[wvid + 1][ch] = acc[ch];
    }
    if (lane == 0 && (wvid == 1 || wvid == 3)) {
#pragma unroll
      for (int ch = 0; ch < 64; ++ch) edgeR[wvid - 1][ch] = acc[ch];
    }
    __syncthreads();

    // ---- depthwise conv (shuffles + edge patch), store post-conv to LDS
    float* dst = isK ? &k_s[pl][0] : &q_s[pl][0];
#pragma unroll
    for (int ch0 = 0; ch0 < 64; ch0 += 4) {
      float vv[4];
#pragma unroll
      for (int j = 0; j < 4; ++j) {
        const int ch = ch0 + j;
        const float mid = acc[ch];
        const float up  = __shfl_up(mid, 1);
        const float dn  = __shfl_down(mid, 1);
        const float lft = (lane == 0)  ? edgeL[wvid][ch] : up;
        const float rgt = (lane == 63) ? edgeR[wvid][ch] : dn;
        vv[j] = wdw[ch * 3 + 0] * lft + wdw[ch * 3 + 1] * mid +
                wdw[ch * 3 + 2] * rgt;
      }
      float4 v4; v4.x = vv[0]; v4.y = vv[1]; v4.z = vv[2]; v4.w = vv[3];
      *(float4*)(dst + ch0) = v4;
    }
    __syncthreads();

    // ---- Gram accumulate: thread tile (c0..c0+3) x (d0..d0+3)
    const int c0 = (tid & 15) << 2;
    const int d0 = (tid >> 4) << 2;
#pragma unroll 4
    for (int l = 0; l < 128; ++l) {
      const float4 qv = *(const float4*)&q_s[l][c0];
      const float4 kv = *(const float4*)&k_s[l][d0];
      g[0]  = fmaf(qv.x, kv.x, g[0]);  g[1]  = fmaf(qv.x, kv.y, g[1]);
      g[2]  = fmaf(qv.x, kv.z, g[2]);  g[3]  = fmaf(qv.x, kv.w, g[3]);
      g[4]  = fmaf(qv.y, kv.x, g[4]);  g[5]  = fmaf(qv.y, kv.y, g[5]);
      g[6]  = fmaf(qv.y, kv.z, g[6]);  g[7]  = fmaf(qv.y, kv.w, g[7]);
      g[8]  = fmaf(qv.z, kv.x, g[8]);  g[9]  = fmaf(qv.z, kv.y, g[9]);
      g[10] = fmaf(qv.z, kv.z, g[10]); g[11] = fmaf(qv.z, kv.w, g[11]);
      g[12] = fmaf(qv.w, kv.x, g[12]); g[13] = fmaf(qv.w, kv.y, g[13]);
      g[14] = fmaf(qv.w, kv.z, g[14]); g[15] = fmaf(qv.w, kv.w, g[15]);
    }
    // ---- norm partials (waves 0,1 only)
    if (tid < 64) {
#pragma unroll 4
      for (int l = 0; l < 128; ++l) { const float v = q_s[l][tid]; nrm = fmaf(v, v, nrm); }
    } else if (tid < 128) {
#pragma unroll 4
      for (int l = 0; l < 128; ++l) { const float v = k_s[l][tid - 64]; nrm = fmaf(v, v, nrm); }
    }
  }

  // ---- reduce to global
  {
    const int c0 = (tid & 15) << 2;
    const int d0 = (tid >> 4) << 2;
    float* Gb = G + b * 4096;
#pragma unroll
    for (int i = 0; i < 4; ++i)
#pragma unroll
      for (int j = 0; j < 4; ++j)
        atomicAdd(&Gb[(c0 + i) * 64 + (d0 + j)], g[i * 4 + j]);
  }
  if (tid < 64)       atomicAdd(&nq[b * 64 + tid], nrm);
  else if (tid < 128) atomicAdd(&nk[b * 64 + (tid - 64)], nrm);
}

// ---------------- Kernel B: logits -> softmax -> M = w_proj @ attn ----------
__global__ void attn_proj_kernel(const float* __restrict__ G,
                                 const float* __restrict__ nq,
                                 const float* __restrict__ nk,
                                 const float* __restrict__ w_proj,
                                 const float* __restrict__ temperature,
                                 float* __restrict__ M) {
  __shared__ float attn_s[64][65];
  __shared__ float invq_s[64];
  __shared__ float invk_s[64];
  const int b = blockIdx.x;
  const int tid = threadIdx.x;
  if (tid < 64)       invq_s[tid]      = 1.f / fmaxf(sqrtf(nq[b * 64 + tid]), 1e-12f);
  else if (tid < 128) invk_s[tid - 64] = 1.f / fmaxf(sqrtf(nk[b * 64 + tid - 64]), 1e-12f);
  __syncthreads();
  const float temp = temperature[b];
  if (tid < 64) {
    const int c = tid;
    const float* Gr = G + b * 4096 + c * 64;
    const float iq = invq_s[c] * temp;
    float z[64];
    float m = -1e30f;
#pragma unroll
    for (int d = 0; d < 64; ++d) { z[d] = Gr[d] * iq * invk_s[d]; m = fmaxf(m, z[d]); }
    float s = 0.f;
#pragma unroll
    for (int d = 0; d < 64; ++d) { z[d] = expf(z[d] - m); s += z[d]; }
    const float inv = 1.f / s;
#pragma unroll
    for (int d = 0; d < 64; ++d) attn_s[c][d] = z[d] * inv;
  }
  __syncthreads();
  const int o = tid & 63;
  const int dg = tid >> 6;
  for (int d = dg * 16; d < dg * 16 + 16; ++d) {
    float s = 0.f;
#pragma unroll
    for (int c = 0; c < 64; ++c) s = fmaf(w_proj[o * 64 + c], attn_s[c][d], s);
    M[b * 4096 + o * 64 + d] = s;
  }
}

// ---------------- Kernel C: vp GEMM -> dwconv (shuffle) -> out = M @ v ------
// grid = NB * (LLEN/256), 256 threads, one position per thread.
__global__ __launch_bounds__(256, 2) void out_kernel(
    const float* __restrict__ x, const float* __restrict__ w_kv,
    const float* __restrict__ w_kv_dw, const float* __restrict__ M,
    float* __restrict__ out) {
  __shared__ float edgeL[4][64];
  __shared__ float edgeR[4][64];
  const int tid  = threadIdx.x;
  const int lane = tid & 63;
  const int wvid = tid >> 6;
  const int nchunk = LLEN / 256;
  const int b     = blockIdx.x / nchunk;
  const int chunk = blockIdx.x % nchunk;
  const int l0 = chunk * 256;
  const int p  = l0 + tid;

  const float* xb     = x + (size_t)b * CDIM * LLEN;
  const float* wv_mat = w_kv + 64 * 64;       // v rows 64..127
  const float* wv_dw  = w_kv_dw + 64 * 3;
  const float* Mb     = M + b * 4096;

  // stage 1: vp at own position
  float x_reg[64];
#pragma unroll
  for (int ci = 0; ci < 64; ++ci) x_reg[ci] = xb[(size_t)ci * LLEN + p];
  float acc[64];
#pragma unroll
  for (int ch = 0; ch < 64; ++ch) {
    const float* wr = wv_mat + ch * 64;
    float p0 = 0.f, p1 = 0.f, p2 = 0.f, p3 = 0.f;
#pragma unroll
    for (int ci = 0; ci < 64; ci += 4) {
      p0 = fmaf(wr[ci + 0], x_reg[ci + 0], p0);
      p1 = fmaf(wr[ci + 1], x_reg[ci + 1], p1);
      p2 = fmaf(wr[ci + 2], x_reg[ci + 2], p2);
      p3 = fmaf(wr[ci + 3], x_reg[ci + 3], p3);
    }
    acc[ch] = (p0 + p1) + (p2 + p3);
  }
  // halo vp at l0-1 / l0+256 (threads 0..127, one channel each)
  if (tid < 128) {
    const int side = tid >> 6;
    const int hc = lane;
    const int pH = side ? (l0 + 256) : (l0 - 1);
    float hval = 0.f;
    if (pH >= 0 && pH < LLEN) {
      const float* wr = wv_mat + hc * 64;
      float h0 = 0.f, h1 = 0.f, h2 = 0.f, h3 = 0.f;
#pragma unroll
      for (int ci = 0; ci < 64; ci += 4) {
        h0 = fmaf(wr[ci + 0], xb[(size_t)(ci + 0) * LLEN + pH], h0);
        h1 = fmaf(wr[ci + 1], xb[(size_t)(ci + 1) * LLEN + pH], h1);
        h2 = fmaf(wr[ci + 2], xb[(size_t)(ci + 2) * LLEN + pH], h2);
        h3 = fmaf(wr[ci + 3], xb[(size_t)(ci + 3) * LLEN + pH], h3);
      }
      hval = (h0 + h1) + (h2 + h3);
    }
    if (side == 0) edgeL[0][hc] = hval; else edgeR[3][hc] = hval;
  }
  if (lane == 63 && wvid < 3) {
#pragma unroll
    for (int ch = 0; ch < 64; ++ch) edgeL[wvid + 1][ch] = acc[ch];
  }
  if (lane == 0 && wvid > 0) {
#pragma unroll
    for (int ch = 0; ch < 64; ++ch) edgeR[wvid - 1][ch] = acc[ch];
  }
  __syncthreads();
  // depthwise conv in place
#pragma unroll
  for (int ch = 0; ch < 64; ++ch) {
    const float mid = acc[ch];
    const float up  = __shfl_up(mid, 1);
    const float dn  = __shfl_down(mid, 1);
    const float lft = (lane == 0)  ? edgeL[wvid][ch] : up;
    const float rgt = (lane == 63) ? edgeR[wvid][ch] : dn;
    acc[ch] = wv_dw[ch * 3 + 0] * lft + wv_dw[ch * 3 + 1] * mid +
              wv_dw[ch * 3 + 2] * rgt;
  }
  // stage 3: out[o][p] = sum_d M[o][d] * v[d]
  float* ob = out + (size_t)b * CDIM * LLEN;
  for (int o = 0; o < 64; ++o) {
    const float* Mr = Mb + o * 64;
    float s0 = 0.f, s1 = 0.f, s2 = 0.f, s3 = 0.f;
#pragma unroll
    for (int d = 0; d < 64; d += 4) {
      s0 = fmaf(Mr[d + 0], acc[d + 0], s0);
      s1 = fmaf(Mr[d + 1], acc[d + 1], s1);
      s2 = fmaf(Mr[d + 2], acc[d + 2], s2);
      s3 = fmaf(Mr[d + 3], acc[d + 3], s3);
    }
    ob[(size_t)o * LLEN + p] = (s0 + s1) + (s2 + s3);
  }
}

extern "C" void kernel_launch(void* const* d_in, const int* in_sizes, int n_in,
                              void* d_out, int out_size, void* d_ws, size_t ws_size,
                              hipStream_t stream) {
  (void)in_sizes; (void)n_in; (void)out_size; (void)ws_size;
  const float* x           = (const float*)d_in[0];
  const float* w_kv        = (const float*)d_in[1];
  const float* w_kv_dw     = (const float*)d_in[2];
  const float* w_q         = (const float*)d_in[3];
  const float* w_q_dw      = (const float*)d_in[4];
  const float* w_proj      = (const float*)d_in[5];
  const float* temperature = (const float*)d_in[6];
  float* out = (float*)d_out;

  float* G  = (float*)d_ws;        // NB*4096
  float* nq = G + NB * 4096;       // NB*64
  float* nk = nq + NB * 64;        // NB*64
  float* M  = nk + NB * 64;        // NB*4096

  hipMemsetAsync(G, 0, (size_t)(NB * 4096 + 2 * NB * 64) * sizeof(float), stream);
  qk_gram_kernel<<<dim3(NB * 256), dim3(256), 0, stream>>>(
      x, w_kv, w_kv_dw, w_q, w_q_dw, G, nq, nk);
  attn_proj_kernel<<<dim3(NB), dim3(256), 0, stream>>>(
      G, nq, nk, w_proj, temperature, M);
  out_kernel<<<dim3(NB * (LLEN / 256)), dim3(256), 0, stream>>>(
      x, w_kv, w_kv_dw, M, out);
}

// Round 2
// 906.877 us; speedup vs baseline: 7.9070x; 7.9070x over previous
//
#include <hip/hip_runtime.h>

#define LLEN 131072
#define CDIM 64
#define NB 4
#define TP 62            // output positions per tile (64-wide x window incl. halo)
#define TILES 2115       // ceil(131072/62), last tile has 4 valid positions
#define NCH_A 9
#define BLKA 235         // 235*9 = 2115
#define NCH_C 5
#define BLKC 423         // 423*5 = 2115

#define QS_PITCH 68      // pad 64->68: float4-aligned rows, acceptable store conflicts

// ---------------- Kernel A: x->LDS, qk GEMM (8-ch passes) -> shuffle dwconv
// ---------------- -> Gram (reg tile 8x4, l-split) + norms ----------------
__global__ __launch_bounds__(256, 3) void qk_gram_kernel(
    const float* __restrict__ x, const float* __restrict__ w_kv,
    const float* __restrict__ w_kv_dw, const float* __restrict__ w_q,
    const float* __restrict__ w_q_dw, float* __restrict__ G,
    float* __restrict__ nq, float* __restrict__ nk) {
  // smem: x_s[64][64] | q_s[62][68] | k_s[62][68]; reduction scratch aliases front
  __shared__ float smem[64 * 64 + 2 * TP * QS_PITCH];
  float* x_s = smem;                    // [ci][pos], 16 KB
  float* q_s = smem + 4096;             // [l][c], pitch 68
  float* k_s = q_s + TP * QS_PITCH;

  const int tid  = threadIdx.x;
  const int lane = tid & 63;
  const int wv   = __builtin_amdgcn_readfirstlane(threadIdx.x >> 6);  // 0..3, SGPR
  const int b    = blockIdx.y;

  const float* xb   = x + (size_t)b * CDIM * LLEN;
  const float* wmat = (wv < 2) ? w_q : w_kv;       // k = rows 0..63 of w_kv
  const float* wdw  = (wv < 2) ? w_q_dw : w_kv_dw;
  const int chbase  = (wv & 1) * 32;

  // Gram register tile: 8 c x 4 d, two l-halves (tid<128: l 0..30, else 31..61)
  const int c0 = (tid & 7) * 8;
  const int d0 = ((tid >> 3) & 15) * 4;
  const int lbeg = (tid >> 7) ? 31 : 0;
  const int lend = (tid >> 7) ? 62 : 31;

  float gacc[32];
#pragma unroll
  for (int i = 0; i < 32; ++i) gacc[i] = 0.f;
  float nrm = 0.f;

  for (int ck = 0; ck < NCH_A; ++ck) {
    const int tile = blockIdx.x * NCH_A + ck;
    const int p0 = tile * TP;

    // ---- load x window [64 ch][64 pos], pos = p0-1 .. p0+62
    for (int idx = tid; idx < 4096; idx += 256) {
      const int ci = idx >> 6, pp = idx & 63;
      const int p = p0 - 1 + pp;
      float v = 0.f;
      if (p >= 0 && p < LLEN) v = xb[(size_t)ci * LLEN + p];
      x_s[idx] = v;
    }
    __syncthreads();

    // ---- GEMM + dwconv: each wave does 32 channels in 4 passes of 8
#pragma unroll
    for (int pass = 0; pass < 4; ++pass) {
      const int ch0 = chbase + pass * 8;
      float acc[8];
#pragma unroll
      for (int j = 0; j < 8; ++j) acc[j] = 0.f;
#pragma unroll 8
      for (int ci = 0; ci < 64; ++ci) {
        const float xv = x_s[ci * 64 + lane];
        const float* wr = wmat + ci;       // wmat[ch*64+ci], uniform -> s_load
#pragma unroll
        for (int j = 0; j < 8; ++j)
          acc[j] = fmaf(wr[(ch0 + j) * 64], xv, acc[j]);
      }
      // depthwise k=3 via shuffles (lane i holds pre at p0-1+i)
#pragma unroll
      for (int j = 0; j < 8; ++j) {
        const float up = __shfl_up(acc[j], 1);
        const float dn = __shfl_down(acc[j], 1);
        const float w0 = wdw[(ch0 + j) * 3 + 0];
        const float w1 = wdw[(ch0 + j) * 3 + 1];
        const float w2 = wdw[(ch0 + j) * 3 + 2];
        acc[j] = fmaf(w0, up, fmaf(w1, acc[j], w2 * dn));
      }
      if (lane >= 1 && lane <= 62) {
        const int l = lane - 1;
        const bool ok = (p0 + l) < LLEN;
        float* dst = ((wv < 2) ? q_s : k_s) + l * QS_PITCH + ch0;
#pragma unroll
        for (int j = 0; j < 8; ++j) dst[j] = ok ? acc[j] : 0.f;
      }
    }
    __syncthreads();

    // ---- Gram accumulate over this tile's l-range
#pragma unroll 2
    for (int l = lbeg; l < lend; ++l) {
      const float4 qa = *(const float4*)&q_s[l * QS_PITCH + c0];
      const float4 qb = *(const float4*)&q_s[l * QS_PITCH + c0 + 4];
      const float4 kv = *(const float4*)&k_s[l * QS_PITCH + d0];
      const float qv[8] = {qa.x, qa.y, qa.z, qa.w, qb.x, qb.y, qb.z, qb.w};
      const float kk[4] = {kv.x, kv.y, kv.z, kv.w};
#pragma unroll
      for (int i = 0; i < 8; ++i)
#pragma unroll
        for (int j = 0; j < 4; ++j)
          gacc[i * 4 + j] = fmaf(qv[i], kk[j], gacc[i * 4 + j]);
    }
    // ---- norm partials: all 4 waves, each (branch, l-half)
    {
      const float* nsrc = ((wv & 1) == 0) ? q_s : k_s;  // waves 0,2=q; 1,3=k
#pragma unroll 2
      for (int l = lbeg; l < lend; ++l) {
        const float v = nsrc[l * QS_PITCH + lane];
        nrm = fmaf(v, v, nrm);
      }
    }
    __syncthreads();
  }

  // ---- cross-half reduction of Gram in LDS, then atomics
  float* scratch = smem;  // 128*33 = 4224 floats, q_s/k_s/x_s all dead
  if (tid >= 128) {
#pragma unroll
    for (int j = 0; j < 32; ++j) scratch[(tid - 128) * 33 + j] = gacc[j];
  }
  __syncthreads();
  if (tid < 128) {
    float* Gb = G + b * 4096;
#pragma unroll
    for (int j = 0; j < 32; ++j) {
      const float v = gacc[j] + scratch[tid * 33 + j];
      atomicAdd(&Gb[(c0 + (j >> 2)) * 64 + (d0 + (j & 3))], v);
    }
  }
  float* np = ((wv & 1) == 0) ? (nq + b * 64) : (nk + b * 64);
  atomicAdd(&np[lane], nrm);
}

// ---------------- Kernel B: logits -> softmax -> M = w_proj @ attn ----------
__global__ void attn_proj_kernel(const float* __restrict__ G,
                                 const float* __restrict__ nq,
                                 const float* __restrict__ nk,
                                 const float* __restrict__ w_proj,
                                 const float* __restrict__ temperature,
                                 float* __restrict__ M) {
  __shared__ float attn_s[64][65];
  __shared__ float invq_s[64];
  __shared__ float invk_s[64];
  const int b = blockIdx.x;
  const int tid = threadIdx.x;
  if (tid < 64)       invq_s[tid]      = 1.f / fmaxf(sqrtf(nq[b * 64 + tid]), 1e-12f);
  else if (tid < 128) invk_s[tid - 64] = 1.f / fmaxf(sqrtf(nk[b * 64 + tid - 64]), 1e-12f);
  __syncthreads();
  const float temp = temperature[b];
  if (tid < 64) {
    const int c = tid;
    const float* Gr = G + b * 4096 + c * 64;
    const float iq = invq_s[c] * temp;
    float z[64];
    float m = -1e30f;
#pragma unroll
    for (int d = 0; d < 64; ++d) { z[d] = Gr[d] * iq * invk_s[d]; m = fmaxf(m, z[d]); }
    float s = 0.f;
#pragma unroll
    for (int d = 0; d < 64; ++d) { z[d] = expf(z[d] - m); s += z[d]; }
    const float inv = 1.f / s;
#pragma unroll
    for (int d = 0; d < 64; ++d) attn_s[c][d] = z[d] * inv;
  }
  __syncthreads();
  const int o = tid & 63;
  const int dg = tid >> 6;
  for (int d = dg * 16; d < dg * 16 + 16; ++d) {
    float s = 0.f;
#pragma unroll
    for (int c = 0; c < 64; ++c) s = fmaf(w_proj[o * 64 + c], attn_s[c][d], s);
    M[b * 4096 + o * 64 + d] = s;
  }
}

// ---------------- Kernel C: x->LDS, v GEMM -> shuffle dwconv -> out = M @ v --
__global__ __launch_bounds__(256, 4) void out_kernel(
    const float* __restrict__ x, const float* __restrict__ w_kv,
    const float* __restrict__ w_kv_dw, const float* __restrict__ M,
    float* __restrict__ out) {
  __shared__ float x_s[4096];   // [ci][pos]
  __shared__ float v_s[4096];   // [ch][l], l = 0..61 (cols 62,63 unused)

  const int tid  = threadIdx.x;
  const int lane = tid & 63;
  const int wv   = __builtin_amdgcn_readfirstlane(threadIdx.x >> 6);
  const int b    = blockIdx.y;

  const float* xb     = x + (size_t)b * CDIM * LLEN;
  const float* wv_mat = w_kv + 4096;        // v = rows 64..127
  const float* wv_dw  = w_kv_dw + 192;
  const float* Mb     = M + b * 4096;
  float* ob = out + (size_t)b * CDIM * LLEN;

  for (int ck = 0; ck < NCH_C; ++ck) {
    const int tile = blockIdx.x * NCH_C + ck;
    const int p0 = tile * TP;

    for (int idx = tid; idx < 4096; idx += 256) {
      const int ci = idx >> 6, pp = idx & 63;
      const int p = p0 - 1 + pp;
      float v = 0.f;
      if (p >= 0 && p < LLEN) v = xb[(size_t)ci * LLEN + p];
      x_s[idx] = v;
    }
    __syncthreads();

    // v GEMM: wave wv -> channels wv*16 .. wv*16+15 (2 passes of 8)
#pragma unroll
    for (int pass = 0; pass < 2; ++pass) {
      const int ch0 = wv * 16 + pass * 8;
      float acc[8];
#pragma unroll
      for (int j = 0; j < 8; ++j) acc[j] = 0.f;
#pragma unroll 8
      for (int ci = 0; ci < 64; ++ci) {
        const float xv = x_s[ci * 64 + lane];
        const float* wr = wv_mat + ci;
#pragma unroll
        for (int j = 0; j < 8; ++j)
          acc[j] = fmaf(wr[(ch0 + j) * 64], xv, acc[j]);
      }
#pragma unroll
      for (int j = 0; j < 8; ++j) {
        const float up = __shfl_up(acc[j], 1);
        const float dn = __shfl_down(acc[j], 1);
        const float w0 = wv_dw[(ch0 + j) * 3 + 0];
        const float w1 = wv_dw[(ch0 + j) * 3 + 1];
        const float w2 = wv_dw[(ch0 + j) * 3 + 2];
        acc[j] = fmaf(w0, up, fmaf(w1, acc[j], w2 * dn));
      }
      if (lane >= 1 && lane <= 62) {
        const int l = lane - 1;
        const bool ok = (p0 + l) < LLEN;
#pragma unroll
        for (int j = 0; j < 8; ++j)
          v_s[(ch0 + j) * 64 + l] = ok ? acc[j] : 0.f;
      }
    }
    __syncthreads();

    // out GEMM: lane <-> position l, wave wv -> out channels wv*16..+15
    {
      const int l = lane;
      const int p = p0 + l;
      const bool ok = (l < TP) && (p < LLEN);
#pragma unroll
      for (int pass = 0; pass < 2; ++pass) {
        const int o0 = wv * 16 + pass * 8;
        float acc[8];
#pragma unroll
        for (int j = 0; j < 8; ++j) acc[j] = 0.f;
#pragma unroll 8
        for (int d = 0; d < 64; ++d) {
          const float vv = v_s[d * 64 + l];
          const float* mr = Mb + d;          // M[o*64+d], uniform -> s_load
#pragma unroll
          for (int j = 0; j < 8; ++j)
            acc[j] = fmaf(mr[(o0 + j) * 64], vv, acc[j]);
        }
        if (ok) {
#pragma unroll
          for (int j = 0; j < 8; ++j)
            ob[(size_t)(o0 + j) * LLEN + p] = acc[j];
        }
      }
    }
    __syncthreads();
  }
}

extern "C" void kernel_launch(void* const* d_in, const int* in_sizes, int n_in,
                              void* d_out, int out_size, void* d_ws, size_t ws_size,
                              hipStream_t stream) {
  (void)in_sizes; (void)n_in; (void)out_size; (void)ws_size;
  const float* x           = (const float*)d_in[0];
  const float* w_kv        = (const float*)d_in[1];
  const float* w_kv_dw     = (const float*)d_in[2];
  const float* w_q         = (const float*)d_in[3];
  const float* w_q_dw      = (const float*)d_in[4];
  const float* w_proj      = (const float*)d_in[5];
  const float* temperature = (const float*)d_in[6];
  float* out = (float*)d_out;

  float* G  = (float*)d_ws;        // NB*4096
  float* nq = G + NB * 4096;       // NB*64
  float* nk = nq + NB * 64;        // NB*64
  float* M  = nk + NB * 64;        // NB*4096

  hipMemsetAsync(G, 0, (size_t)(NB * 4096 + 2 * NB * 64) * sizeof(float), stream);
  qk_gram_kernel<<<dim3(BLKA, NB), dim3(256), 0, stream>>>(
      x, w_kv, w_kv_dw, w_q, w_q_dw, G, nq, nk);
  attn_proj_kernel<<<dim3(NB), dim3(256), 0, stream>>>(
      G, nq, nk, w_proj, temperature, M);
  out_kernel<<<dim3(BLKC, NB), dim3(256), 0, stream>>>(
      x, w_kv, w_kv_dw, M, out);
}

// Round 3
// 790.005 us; speedup vs baseline: 9.0768x; 1.1479x over previous
//
#include <hip/hip_runtime.h>

#define LLEN 131072
#define CDIM 64
#define NB 4
#define TP 62            // output positions per 64-wide window (1 halo each side)
#define TILES 2115       // 2115*62 = 131130 >= 131072
#define NCH_A 3
#define BLKA 705         // 705*3 = 2115
#define NCH_C 3
#define BLKC 705
#define QS_PITCH 68

// ---------------- prep: transposed weight tables (wT[ci][ch]) ----------------
__global__ void prep_kernel(const float* __restrict__ w_q,
                            const float* __restrict__ w_kv,
                            float* __restrict__ wqT, float* __restrict__ wkT,
                            float* __restrict__ wvT) {
  const int idx = blockIdx.x * 256 + threadIdx.x;  // 0..4095
  const int ci = idx >> 6, ch = idx & 63;
  wqT[ci * 64 + ch] = w_q[ch * 64 + ci];
  wkT[ci * 64 + ch] = w_kv[ch * 64 + ci];
  wvT[ci * 64 + ch] = w_kv[(64 + ch) * 64 + ci];
}

// ---------------- Kernel A: qk GEMM (dwordx16 weights) -> shuffle dwconv
// ---------------- -> Gram (8x4 reg tile, l-split) + norms -------------------
__global__ __launch_bounds__(256, 4) void qk_gram_kernel(
    const float* __restrict__ x, const float* __restrict__ wqT,
    const float* __restrict__ wkT, const float* __restrict__ w_q_dw,
    const float* __restrict__ w_kv_dw, float* __restrict__ G,
    float* __restrict__ nq, float* __restrict__ nk) {
  __shared__ __attribute__((aligned(16))) float smem[2 * TP * QS_PITCH]; // 33.7 KB
  float* q_s = smem;                       // [l][c], pitch 68
  float* k_s = smem + TP * QS_PITCH;

  const int tid  = threadIdx.x;
  const int lane = tid & 63;
  const int wv   = __builtin_amdgcn_readfirstlane(threadIdx.x >> 6);
  const int b    = blockIdx.y;

  const float* xb  = x + (size_t)b * CDIM * LLEN;
  const float* wT  = (wv < 2) ? wqT : wkT;
  const float* wdw = (wv < 2) ? w_q_dw : w_kv_dw;  // k = rows 0..63 of w_kv_dw
  const int chbase = (wv & 1) * 32;
  float* dst_s = (wv < 2) ? q_s : k_s;

  const int c0 = (tid & 7) * 8;
  const int d0 = ((tid >> 3) & 15) * 4;
  const int lbeg = (tid >> 7) ? 31 : 0;
  const int lend = (tid >> 7) ? 62 : 31;

  float gacc[32];
#pragma unroll
  for (int i = 0; i < 32; ++i) gacc[i] = 0.f;
  float nrm = 0.f;

  for (int ck = 0; ck < NCH_A; ++ck) {
    const int p0 = (blockIdx.x * NCH_A + ck) * TP;
    const int p  = p0 - 1 + lane;                 // window position for this lane
    const int pc = min(max(p, 0), LLEN - 1);
    const bool pvalid = (p >= 0) && (p < LLEN);
    const float* xp = xb + pc;

    // ---- GEMM: two passes of 16 channels per wave
#pragma unroll
    for (int pass = 0; pass < 2; ++pass) {
      const int ch0 = chbase + pass * 16;
      float acc[16];
#pragma unroll
      for (int j = 0; j < 16; ++j) acc[j] = 0.f;
#pragma unroll 4
      for (int ci = 0; ci < 64; ++ci) {
        const float xv = xp[(size_t)ci * LLEN];       // coalesced, L1-resident
        const float* wrow = wT + ci * 64 + ch0;       // uniform -> s_load_dwordx16
#pragma unroll
        for (int j = 0; j < 16; ++j) acc[j] = fmaf(wrow[j], xv, acc[j]);
      }
#pragma unroll
      for (int j = 0; j < 16; ++j) acc[j] = pvalid ? acc[j] : 0.f;  // pad = 0
      // depthwise k=3 via shuffles (lane i holds pre-conv at p0-1+i)
#pragma unroll
      for (int j = 0; j < 16; ++j) {
        const int ch = ch0 + j;
        const float up = __shfl_up(acc[j], 1);
        const float dn = __shfl_down(acc[j], 1);
        acc[j] = fmaf(wdw[ch * 3 + 0], up,
                 fmaf(wdw[ch * 3 + 1], acc[j], wdw[ch * 3 + 2] * dn));
      }
      if (lane >= 1 && lane <= 62) {
        const int l = lane - 1;
        const bool ok = (p0 + l) < LLEN;
        float* dst = dst_s + l * QS_PITCH + ch0;
#pragma unroll
        for (int j = 0; j < 16; ++j) dst[j] = ok ? acc[j] : 0.f;
      }
    }
    __syncthreads();

    // ---- Gram accumulate over this tile's l-range
#pragma unroll 2
    for (int l = lbeg; l < lend; ++l) {
      const float4 qa = *(const float4*)&q_s[l * QS_PITCH + c0];
      const float4 qb = *(const float4*)&q_s[l * QS_PITCH + c0 + 4];
      const float4 kv = *(const float4*)&k_s[l * QS_PITCH + d0];
      const float qv[8] = {qa.x, qa.y, qa.z, qa.w, qb.x, qb.y, qb.z, qb.w};
      const float kk[4] = {kv.x, kv.y, kv.z, kv.w};
#pragma unroll
      for (int i = 0; i < 8; ++i)
#pragma unroll
        for (int j = 0; j < 4; ++j)
          gacc[i * 4 + j] = fmaf(qv[i], kk[j], gacc[i * 4 + j]);
    }
    // ---- norm partials: waves 0,2 = q; waves 1,3 = k
    {
      const float* nsrc = ((wv & 1) == 0) ? q_s : k_s;
#pragma unroll 2
      for (int l = lbeg; l < lend; ++l) {
        const float v = nsrc[l * QS_PITCH + lane];
        nrm = fmaf(v, v, nrm);
      }
    }
    __syncthreads();
  }

  // ---- cross-half reduction of Gram in LDS, then atomics
  float* scratch = smem;  // 128*33*4 = 16.9 KB, q_s/k_s dead
  if (tid >= 128) {
#pragma unroll
    for (int j = 0; j < 32; ++j) scratch[(tid - 128) * 33 + j] = gacc[j];
  }
  __syncthreads();
  if (tid < 128) {
    float* Gb = G + b * 4096;
#pragma unroll
    for (int j = 0; j < 32; ++j) {
      const float v = gacc[j] + scratch[tid * 33 + j];
      atomicAdd(&Gb[(c0 + (j >> 2)) * 64 + (d0 + (j & 3))], v);
    }
  }
  float* np = ((wv & 1) == 0) ? (nq + b * 64) : (nk + b * 64);
  atomicAdd(&np[lane], nrm);
}

// ---------------- Kernel B: logits -> softmax -> MT = (w_proj @ attn)^T -----
__global__ void attn_proj_kernel(const float* __restrict__ G,
                                 const float* __restrict__ nq,
                                 const float* __restrict__ nk,
                                 const float* __restrict__ w_proj,
                                 const float* __restrict__ temperature,
                                 float* __restrict__ MT) {
  __shared__ float attn_s[64][65];
  __shared__ float invq_s[64];
  __shared__ float invk_s[64];
  const int b = blockIdx.x;
  const int tid = threadIdx.x;
  if (tid < 64)       invq_s[tid]      = 1.f / fmaxf(sqrtf(nq[b * 64 + tid]), 1e-12f);
  else if (tid < 128) invk_s[tid - 64] = 1.f / fmaxf(sqrtf(nk[b * 64 + tid - 64]), 1e-12f);
  __syncthreads();
  const float temp = temperature[b];
  if (tid < 64) {
    const int c = tid;
    const float* Gr = G + b * 4096 + c * 64;
    const float iq = invq_s[c] * temp;
    float z[64];
    float m = -1e30f;
#pragma unroll
    for (int d = 0; d < 64; ++d) { z[d] = Gr[d] * iq * invk_s[d]; m = fmaxf(m, z[d]); }
    float s = 0.f;
#pragma unroll
    for (int d = 0; d < 64; ++d) { z[d] = expf(z[d] - m); s += z[d]; }
    const float inv = 1.f / s;
#pragma unroll
    for (int d = 0; d < 64; ++d) attn_s[c][d] = z[d] * inv;
  }
  __syncthreads();
  const int o = tid & 63;
  const int dg = tid >> 6;
  for (int d = dg * 16; d < dg * 16 + 16; ++d) {
    float s = 0.f;
#pragma unroll
    for (int c = 0; c < 64; ++c) s = fmaf(w_proj[o * 64 + c], attn_s[c][d], s);
    MT[b * 4096 + d * 64 + o] = s;   // transposed for kernel C's scalar loads
  }
}

// ---------------- Kernel C: v GEMM -> shuffle dwconv -> out = M @ v ---------
__global__ __launch_bounds__(256, 4) void out_kernel(
    const float* __restrict__ x, const float* __restrict__ wvT,
    const float* __restrict__ w_kv_dw, const float* __restrict__ MT,
    float* __restrict__ out) {
  __shared__ float v_s[64 * 64];   // [ch][l], 16 KB (cols 62,63 unused)

  const int tid  = threadIdx.x;
  const int lane = tid & 63;
  const int wv   = __builtin_amdgcn_readfirstlane(threadIdx.x >> 6);
  const int b    = blockIdx.y;

  const float* xb    = x + (size_t)b * CDIM * LLEN;
  const float* wv_dw = w_kv_dw + 192;       // v = rows 64..127
  const float* MTb   = MT + b * 4096;
  float* ob = out + (size_t)b * CDIM * LLEN;

  for (int ck = 0; ck < NCH_C; ++ck) {
    const int p0 = (blockIdx.x * NCH_C + ck) * TP;
    const int p  = p0 - 1 + lane;
    const int pc = min(max(p, 0), LLEN - 1);
    const bool pvalid = (p >= 0) && (p < LLEN);
    const float* xp = xb + pc;

    if (ck) __syncthreads();   // previous out-GEMM reads of v_s must finish

    // ---- v GEMM: 16 channels per wave, one pass
    {
      const int ch0 = wv * 16;
      float acc[16];
#pragma unroll
      for (int j = 0; j < 16; ++j) acc[j] = 0.f;
#pragma unroll 4
      for (int ci = 0; ci < 64; ++ci) {
        const float xv = xp[(size_t)ci * LLEN];
        const float* wrow = wvT + ci * 64 + ch0;   // s_load_dwordx16
#pragma unroll
        for (int j = 0; j < 16; ++j) acc[j] = fmaf(wrow[j], xv, acc[j]);
      }
#pragma unroll
      for (int j = 0; j < 16; ++j) acc[j] = pvalid ? acc[j] : 0.f;
#pragma unroll
      for (int j = 0; j < 16; ++j) {
        const int ch = ch0 + j;
        const float up = __shfl_up(acc[j], 1);
        const float dn = __shfl_down(acc[j], 1);
        acc[j] = fmaf(wv_dw[ch * 3 + 0], up,
                 fmaf(wv_dw[ch * 3 + 1], acc[j], wv_dw[ch * 3 + 2] * dn));
      }
      if (lane >= 1 && lane <= 62) {
        const int l = lane - 1;
        const bool ok = (p0 + l) < LLEN;
#pragma unroll
        for (int j = 0; j < 16; ++j)
          v_s[(ch0 + j) * 64 + l] = ok ? acc[j] : 0.f;  // conflict-free stores
      }
    }
    __syncthreads();

    // ---- out GEMM: lane = position l, wave -> out channels wv*16..+15
    {
      const int l = lane;
      const int pp = p0 + l;
      const bool ok = (l < TP) && (pp < LLEN);
      const int o0 = wv * 16;
      float oacc[16];
#pragma unroll
      for (int j = 0; j < 16; ++j) oacc[j] = 0.f;
#pragma unroll 4
      for (int d = 0; d < 64; ++d) {
        const float vvv = v_s[d * 64 + l];         // conflict-free
        const float* mr = MTb + d * 64 + o0;       // s_load_dwordx16
#pragma unroll
        for (int j = 0; j < 16; ++j) oacc[j] = fmaf(mr[j], vvv, oacc[j]);
      }
      if (ok) {
#pragma unroll
        for (int j = 0; j < 16; ++j)
          ob[(size_t)(o0 + j) * LLEN + pp] = oacc[j];
      }
    }
  }
}

extern "C" void kernel_launch(void* const* d_in, const int* in_sizes, int n_in,
                              void* d_out, int out_size, void* d_ws, size_t ws_size,
                              hipStream_t stream) {
  (void)in_sizes; (void)n_in; (void)out_size; (void)ws_size;
  const float* x           = (const float*)d_in[0];
  const float* w_kv        = (const float*)d_in[1];
  const float* w_kv_dw     = (const float*)d_in[2];
  const float* w_q         = (const float*)d_in[3];
  const float* w_q_dw      = (const float*)d_in[4];
  const float* w_proj      = (const float*)d_in[5];
  const float* temperature = (const float*)d_in[6];
  float* out = (float*)d_out;

  float* G   = (float*)d_ws;         // NB*4096
  float* nq  = G + NB * 4096;        // NB*64
  float* nk  = nq + NB * 64;         // NB*64
  float* MT  = nk + NB * 64;         // NB*4096
  float* wqT = MT + NB * 4096;       // 4096
  float* wkT = wqT + 4096;           // 4096
  float* wvT = wkT + 4096;           // 4096

  hipMemsetAsync(G, 0, (size_t)(NB * 4096 + 2 * NB * 64) * sizeof(float), stream);
  prep_kernel<<<dim3(16), dim3(256), 0, stream>>>(w_q, w_kv, wqT, wkT, wvT);
  qk_gram_kernel<<<dim3(BLKA, NB), dim3(256), 0, stream>>>(
      x, wqT, wkT, w_q_dw, w_kv_dw, G, nq, nk);
  attn_proj_kernel<<<dim3(NB), dim3(256), 0, stream>>>(
      G, nq, nk, w_proj, temperature, MT);
  out_kernel<<<dim3(BLKC, NB), dim3(256), 0, stream>>>(
      x, wvT, w_kv_dw, MT, out);
}